// Round 1
// baseline (326.991 us; speedup 1.0000x reference)
//
#include <hip/hip_runtime.h>
#include <hip/hip_bf16.h>

typedef __bf16 bf16_t;
typedef __bf16 bf16x8 __attribute__((ext_vector_type(8)));
typedef float  f32x4  __attribute__((ext_vector_type(4)));
typedef float  f32x2  __attribute__((ext_vector_type(2)));

#define S_LEN 4096
#define NH    8
#define DH    64
#define DE    512

// ---------------------------------------------------------------------------
// GEMM tile params (both projection GEMMs): 128x128 block tile, BK=32,
// 4 waves (2x2), each wave 64x64 = 4x4 MFMA fragments of 16x16x32 bf16.
// ---------------------------------------------------------------------------
#define BM 128
#define BN 128
#define BK 32
#define LDP 40   // padded LDS k-stride in bf16 elements (80B rows, 16B aligned)

static __device__ __forceinline__ void stage16_f32(bf16_t* dst, const float* src) {
    // load 16 f32, convert to bf16, store as 2x16B into LDS
    const float4 v0 = *reinterpret_cast<const float4*>(src + 0);
    const float4 v1 = *reinterpret_cast<const float4*>(src + 4);
    const float4 v2 = *reinterpret_cast<const float4*>(src + 8);
    const float4 v3 = *reinterpret_cast<const float4*>(src + 12);
    bf16x8 lo, hi;
    lo[0]=(bf16_t)v0.x; lo[1]=(bf16_t)v0.y; lo[2]=(bf16_t)v0.z; lo[3]=(bf16_t)v0.w;
    lo[4]=(bf16_t)v1.x; lo[5]=(bf16_t)v1.y; lo[6]=(bf16_t)v1.z; lo[7]=(bf16_t)v1.w;
    hi[0]=(bf16_t)v2.x; hi[1]=(bf16_t)v2.y; hi[2]=(bf16_t)v2.z; hi[3]=(bf16_t)v2.w;
    hi[4]=(bf16_t)v3.x; hi[5]=(bf16_t)v3.y; hi[6]=(bf16_t)v3.z; hi[7]=(bf16_t)v3.w;
    *reinterpret_cast<bf16x8*>(dst + 0) = lo;
    *reinterpret_cast<bf16x8*>(dst + 8) = hi;
}

// ---------------------------------------------------------------------------
// Kernel 1: qkv = x @ w_in^T + b_in ; scatter to Q [h][s][64], K [h][s][64],
//           V^T [h][64][s]   (all bf16)
// ---------------------------------------------------------------------------
__global__ __launch_bounds__(256) void qkv_gemm(
    const float* __restrict__ X,     // [4096][512]
    const float* __restrict__ Win,   // [1536][512]
    const float* __restrict__ bin,   // [1536]
    bf16_t* __restrict__ qw,
    bf16_t* __restrict__ kw,
    bf16_t* __restrict__ vtw)
{
    __shared__ bf16_t As[BM * LDP];
    __shared__ bf16_t Bs[BN * LDP];

    const int tid  = threadIdx.x;
    const int lane = tid & 63;
    const int w    = tid >> 6;
    const int wr   = w >> 1, wc = w & 1;
    const int row0 = blockIdx.y * BM;
    const int col0 = blockIdx.x * BN;

    const int fr = lane & 15;          // fragment row/col (A row, B col, D col)
    const int fo = (lane >> 4) * 8;    // fragment k offset
    const int cr = (lane >> 4) * 4;    // D row base

    const int sr = tid >> 1;           // staging row 0..127
    const int sc = (tid & 1) * 16;     // staging col 0 or 16

    f32x4 acc[4][4] = {};

    for (int k0 = 0; k0 < DE; k0 += BK) {
        stage16_f32(As + sr * LDP + sc, X   + (row0 + sr) * DE + k0 + sc);
        stage16_f32(Bs + sr * LDP + sc, Win + (col0 + sr) * DE + k0 + sc);
        __syncthreads();

        bf16x8 af[4], bf[4];
        #pragma unroll
        for (int m = 0; m < 4; ++m)
            af[m] = *reinterpret_cast<const bf16x8*>(As + (wr * 64 + m * 16 + fr) * LDP + fo);
        #pragma unroll
        for (int n = 0; n < 4; ++n)
            bf[n] = *reinterpret_cast<const bf16x8*>(Bs + (wc * 64 + n * 16 + fr) * LDP + fo);
        #pragma unroll
        for (int m = 0; m < 4; ++m)
            #pragma unroll
            for (int n = 0; n < 4; ++n)
                acc[m][n] = __builtin_amdgcn_mfma_f32_16x16x32_bf16(af[m], bf[n], acc[m][n], 0, 0, 0);
        __syncthreads();
    }

    // epilogue: add bias, scatter to Q/K/V^T (branch is uniform per block:
    // col0 is a multiple of 128, 512 boundaries are multiples of 128)
    #pragma unroll
    for (int m = 0; m < 4; ++m) {
        #pragma unroll
        for (int n = 0; n < 4; ++n) {
            const int col = col0 + wc * 64 + n * 16 + fr;
            const float b = bin[col];
            const int part = col >> 9;       // 0=Q, 1=K, 2=V
            const int cd   = col & 511;
            const int h    = cd >> 6;
            const int d    = cd & 63;
            #pragma unroll
            for (int r = 0; r < 4; ++r) {
                const int row = row0 + wr * 64 + m * 16 + cr + r;   // s index
                const float v = acc[m][n][r] + b;
                const bf16_t bv = (bf16_t)v;
                if (part == 0)      qw [(h * S_LEN + row) * DH + d] = bv;
                else if (part == 1) kw [(h * S_LEN + row) * DH + d] = bv;
                else                vtw[(h * DH + d) * S_LEN + row] = bv;
            }
        }
    }
}

// ---------------------------------------------------------------------------
// Kernel 2: attention with softmax over the HEADS axis.
// One block per 16-query tile (256 blocks), 8 waves = 8 heads.
// Per 64-key tile: S = Q K^T (MFMA), e = exp(S/8) -> LDS, cross-head
// denominator, w = e * rden -> bf16 -> PV MFMA with V^T.
// ---------------------------------------------------------------------------
__global__ __launch_bounds__(512) void attn_kernel(
    const bf16_t* __restrict__ qw,    // [h][s][64]
    const bf16_t* __restrict__ kw,    // [h][s][64]
    const bf16_t* __restrict__ vtw,   // [h][64][s]
    const int*    __restrict__ causal_p,
    bf16_t* __restrict__ attn)        // [s][512]
{
    __shared__ float e_lds[NH][16][68];   // 68 = 64 + 4 pad (2-way banks only)
    __shared__ float rden[16][68];

    const int tid  = threadIdx.x;
    const int lane = tid & 63;
    const int h    = tid >> 6;            // head = wave id
    const int q0   = blockIdx.x * 16;
    const int causal = causal_p[0];

    const int fr = lane & 15;
    const int fo = (lane >> 4) * 8;
    const int cr = (lane >> 4) * 4;

    // Q fragments for this head's 16 queries (A-operand, d = 0..63)
    bf16x8 aq0 = *reinterpret_cast<const bf16x8*>(qw + ((h * S_LEN) + q0 + fr) * DH + fo);
    bf16x8 aq1 = *reinterpret_cast<const bf16x8*>(qw + ((h * S_LEN) + q0 + fr) * DH + 32 + fo);

    f32x4 o[4] = {};

    for (int kt = 0; kt < S_LEN / 64; ++kt) {
        const int k0 = kt * 64;

        // ---- QK^T : 4 sub-tiles of 16 keys, K-dim = 64 (2 MFMAs each) ----
        f32x4 s[4];
        #pragma unroll
        for (int kk = 0; kk < 4; ++kk) {
            const bf16_t* kbase = kw + ((h * S_LEN) + k0 + kk * 16 + fr) * DH;
            bf16x8 b0 = *reinterpret_cast<const bf16x8*>(kbase + fo);
            bf16x8 b1 = *reinterpret_cast<const bf16x8*>(kbase + 32 + fo);
            f32x4 z = {};
            z = __builtin_amdgcn_mfma_f32_16x16x32_bf16(aq0, b0, z, 0, 0, 0);
            z = __builtin_amdgcn_mfma_f32_16x16x32_bf16(aq1, b1, z, 0, 0, 0);
            s[kk] = z;
        }

        __syncthreads();   // previous tile's LDS readers are done

        // ---- e = exp(s/8) -> LDS (D-layout: row = cr+r, col = kk*16+fr) ----
        #pragma unroll
        for (int kk = 0; kk < 4; ++kk) {
            #pragma unroll
            for (int r = 0; r < 4; ++r) {
                float e = __expf(s[kk][r] * 0.125f);
                if (causal) {
                    const int ki = k0 + kk * 16 + fr;
                    const int qi = q0 + cr + r;
                    if (ki > qi) e = 0.f;
                }
                e_lds[h][cr + r][kk * 16 + fr] = e;
            }
        }
        __syncthreads();

        // ---- cross-head denominator: 1024 (q,k) pairs / 512 threads ----
        {
            const int idx = tid * 2;
            const int dq = idx >> 6;
            const int dk = idx & 63;
            f32x2 sum = {0.f, 0.f};
            #pragma unroll
            for (int hh = 0; hh < NH; ++hh) {
                f32x2 v = *reinterpret_cast<const f32x2*>(&e_lds[hh][dq][dk]);
                sum[0] += v[0];
                sum[1] += v[1];
            }
            f32x2 rd;
            rd[0] = (sum[0] > 0.f) ? 1.f / sum[0] : 0.f;
            rd[1] = (sum[1] > 0.f) ? 1.f / sum[1] : 0.f;
            *reinterpret_cast<f32x2*>(&rden[dq][dk]) = rd;
        }
        __syncthreads();

        // ---- PV: w = e * rden (A-layout), o += w @ V ----
        #pragma unroll
        for (int c = 0; c < 2; ++c) {
            f32x4 e0 = *reinterpret_cast<const f32x4*>(&e_lds[h][fr][c * 32 + fo]);
            f32x4 e1 = *reinterpret_cast<const f32x4*>(&e_lds[h][fr][c * 32 + fo + 4]);
            f32x4 d0 = *reinterpret_cast<const f32x4*>(&rden[fr][c * 32 + fo]);
            f32x4 d1 = *reinterpret_cast<const f32x4*>(&rden[fr][c * 32 + fo + 4]);
            bf16x8 pa;
            pa[0] = (bf16_t)(e0[0] * d0[0]);
            pa[1] = (bf16_t)(e0[1] * d0[1]);
            pa[2] = (bf16_t)(e0[2] * d0[2]);
            pa[3] = (bf16_t)(e0[3] * d0[3]);
            pa[4] = (bf16_t)(e1[0] * d1[0]);
            pa[5] = (bf16_t)(e1[1] * d1[1]);
            pa[6] = (bf16_t)(e1[2] * d1[2]);
            pa[7] = (bf16_t)(e1[3] * d1[3]);
            #pragma unroll
            for (int n = 0; n < 4; ++n) {
                const bf16_t* vb = vtw + (h * DH + n * 16 + fr) * S_LEN + k0 + c * 32 + fo;
                bf16x8 bv = *reinterpret_cast<const bf16x8*>(vb);
                o[n] = __builtin_amdgcn_mfma_f32_16x16x32_bf16(pa, bv, o[n], 0, 0, 0);
            }
        }
    }

    // ---- write attention output: attn[s][h*64 + d], bf16 ----
    #pragma unroll
    for (int n = 0; n < 4; ++n) {
        #pragma unroll
        for (int r = 0; r < 4; ++r) {
            const int row = q0 + cr + r;
            const int col = h * 64 + n * 16 + fr;
            attn[row * DE + col] = (bf16_t)o[n][r];
        }
    }
}

// ---------------------------------------------------------------------------
// Kernel 3: out = attn @ w_out^T + b_out   (f32 output)
// ---------------------------------------------------------------------------
__global__ __launch_bounds__(256) void out_gemm(
    const bf16_t* __restrict__ Aattn,  // [4096][512] bf16
    const float*  __restrict__ Wout,   // [512][512]
    const float*  __restrict__ bout,   // [512]
    float* __restrict__ out)           // [4096][512]
{
    __shared__ bf16_t As[BM * LDP];
    __shared__ bf16_t Bs[BN * LDP];

    const int tid  = threadIdx.x;
    const int lane = tid & 63;
    const int w    = tid >> 6;
    const int wr   = w >> 1, wc = w & 1;
    const int row0 = blockIdx.y * BM;
    const int col0 = blockIdx.x * BN;

    const int fr = lane & 15;
    const int fo = (lane >> 4) * 8;
    const int cr = (lane >> 4) * 4;

    const int sr = tid >> 1;
    const int sc = (tid & 1) * 16;

    f32x4 acc[4][4] = {};

    for (int k0 = 0; k0 < DE; k0 += BK) {
        // A is already bf16: copy 16 elems (32B) straight into LDS
        {
            const uint4* g = reinterpret_cast<const uint4*>(Aattn + (row0 + sr) * DE + k0 + sc);
            uint4 v0 = g[0];
            uint4 v1 = g[1];
            *reinterpret_cast<uint4*>(As + sr * LDP + sc + 0) = v0;
            *reinterpret_cast<uint4*>(As + sr * LDP + sc + 8) = v1;
        }
        stage16_f32(Bs + sr * LDP + sc, Wout + (col0 + sr) * DE + k0 + sc);
        __syncthreads();

        bf16x8 af[4], bf[4];
        #pragma unroll
        for (int m = 0; m < 4; ++m)
            af[m] = *reinterpret_cast<const bf16x8*>(As + (wr * 64 + m * 16 + fr) * LDP + fo);
        #pragma unroll
        for (int n = 0; n < 4; ++n)
            bf[n] = *reinterpret_cast<const bf16x8*>(Bs + (wc * 64 + n * 16 + fr) * LDP + fo);
        #pragma unroll
        for (int m = 0; m < 4; ++m)
            #pragma unroll
            for (int n = 0; n < 4; ++n)
                acc[m][n] = __builtin_amdgcn_mfma_f32_16x16x32_bf16(af[m], bf[n], acc[m][n], 0, 0, 0);
        __syncthreads();
    }

    #pragma unroll
    for (int m = 0; m < 4; ++m) {
        #pragma unroll
        for (int n = 0; n < 4; ++n) {
            const int col = col0 + wc * 64 + n * 16 + fr;
            const float b = bout[col];
            #pragma unroll
            for (int r = 0; r < 4; ++r) {
                const int row = row0 + wr * 64 + m * 16 + cr + r;
                out[row * DE + col] = acc[m][n][r] + b;
            }
        }
    }
}

// ---------------------------------------------------------------------------
// Launch
// ---------------------------------------------------------------------------
extern "C" void kernel_launch(void* const* d_in, const int* in_sizes, int n_in,
                              void* d_out, int out_size, void* d_ws, size_t ws_size,
                              hipStream_t stream) {
    const float* x     = (const float*)d_in[0];
    const float* w_in  = (const float*)d_in[1];
    const float* b_in  = (const float*)d_in[2];
    const float* w_out = (const float*)d_in[3];
    const float* b_out = (const float*)d_in[4];
    const int*   causal = (const int*)d_in[5];
    float* out = (float*)d_out;

    // workspace layout (bf16): Q [8][4096][64], K [8][4096][64],
    // V^T [8][64][4096], attn [4096][512]  -> 4 x 2M elems = 16 MB
    bf16_t* qw   = (bf16_t*)d_ws;
    bf16_t* kw   = qw  + NH * S_LEN * DH;
    bf16_t* vtw  = kw  + NH * S_LEN * DH;
    bf16_t* attn = vtw + NH * S_LEN * DH;

    dim3 g1(3 * DE / BN, S_LEN / BM);   // (12, 32)
    qkv_gemm<<<g1, 256, 0, stream>>>(x, w_in, b_in, qw, kw, vtw);

    attn_kernel<<<S_LEN / 16, 512, 0, stream>>>(qw, kw, vtw, causal, attn);

    dim3 g3(DE / BN, S_LEN / BM);       // (4, 32)
    out_gemm<<<g3, 256, 0, stream>>>(attn, w_out, b_out, out);
}